// Round 5
// baseline (275.228 us; speedup 1.0000x reference)
//
#include <hip/hip_runtime.h>
#include <math.h>

#define BB 16
#define NP 8192
#define NV 42
#define NF 80
#define FEAT 256
#define PPB 64           // points per block (mvc)
#define CHF 10           // faces per wave-chunk
#define WST 67           // padded LDS stride for wj

// Icosphere(level=1) face table — deterministic from ico_sphere_np(1)
// (validated end-to-end by round-4 pass, absmax 0.031).
#define FACE_LIST \
 {0,12,14},{11,13,12},{5,14,13},{12,13,14}, \
 {0,14,16},{5,15,14},{1,16,15},{14,15,16}, \
 {0,16,18},{1,17,16},{7,18,17},{16,17,18}, \
 {0,18,20},{7,19,18},{10,20,19},{18,19,20}, \
 {0,20,12},{10,21,20},{11,12,21},{20,21,12}, \
 {1,15,23},{5,22,15},{9,23,22},{15,22,23}, \
 {5,13,25},{11,24,13},{4,25,24},{13,24,25}, \
 {11,21,27},{10,26,21},{2,27,26},{21,26,27}, \
 {10,19,29},{7,28,19},{6,29,28},{19,28,29}, \
 {7,17,31},{1,30,17},{8,31,30},{17,30,31}, \
 {3,32,34},{9,33,32},{4,34,33},{32,33,34}, \
 {3,34,36},{4,35,34},{2,36,35},{34,35,36}, \
 {3,36,38},{2,37,36},{6,38,37},{36,37,38}, \
 {3,38,40},{6,39,38},{8,40,39},{38,39,40}, \
 {3,40,32},{8,41,40},{9,32,41},{40,41,32}, \
 {4,33,25},{9,22,33},{5,25,22},{33,22,25}, \
 {2,35,27},{4,24,35},{11,27,24},{35,24,27}, \
 {6,37,29},{2,26,37},{10,29,26},{37,26,29}, \
 {8,39,31},{6,28,39},{7,31,28},{39,28,31}, \
 {9,41,23},{8,30,41},{1,23,30},{41,30,23}

constexpr int FC[NF][3] = { FACE_LIST };               // compile-time
static __device__ const int FR[NF][3] = { FACE_LIST }; // runtime (cold paths)

constexpr unsigned long long chunk_vmask(int q) {
  unsigned long long m = 0;
  for (int f = q * CHF; f < q * CHF + CHF; ++f)
    for (int k = 0; k < 3; ++k) m |= 1ull << FC[f][k];
  return m;
}
constexpr int popcnt_c(unsigned long long m) {
  int c = 0;
  for (int i = 0; i < 64; i++) c += (int)((m >> i) & 1ull);
  return c;
}
constexpr int nth_bit_c(unsigned long long m, int n) {
  for (int i = 0; i < 64; i++)
    if ((m >> i) & 1ull) { if (n == 0) return i; --n; }
  return -1;
}
constexpr int slot_of_c(unsigned long long m, int c) {
  int cnt = 0;
  for (int i = 0; i < c; i++) cnt += (int)((m >> i) & 1ull);
  return cnt;
}

__device__ __forceinline__ float rcp_f(float x)  { return __builtin_amdgcn_rcpf(x); }
__device__ __forceinline__ float rsq_f(float x)  { return __builtin_amdgcn_rsqf(x); }
__device__ __forceinline__ float sqrt_f(float x) { return __builtin_amdgcn_sqrtf(x); }

// theta = 2*asin(x), x in [0,1). Branchless, |err|~1e-5.
__device__ __forceinline__ float theta_from_x(float x) {
  bool big = x > 0.5f;
  float z = big ? fmaf(-0.5f, x, 0.5f) : x * x;
  float s = big ? sqrt_f(z) : x;
  float P = fmaf(z, 0.022371875f, 0.030381944f);
  P = fmaf(z, P, 0.044642857f);
  P = fmaf(z, P, 0.075f);
  P = fmaf(z, P, 0.16666667f);
  float r = fmaf(s * z, P, s);
  return big ? fmaf(-4.f, r, 3.14159265358979f) : 2.f * r;
}

// ---- per-chunk vertex hoist into COMPACT slot arrays ----
template<int Q, int S>
struct VtxS {
  static constexpr unsigned long long M = chunk_vmask(Q);
  static constexpr int NT = popcnt_c(M);
  static __device__ __forceinline__ void go(const float4* vpos,
      float qx, float qy, float qz,
      float (&ux)[NT], float (&uy)[NT], float (&uz)[NT], float (&dd)[NT],
      unsigned long long& closeMask) {
    if constexpr (S < NT) {
      constexpr int C = nth_bit_c(M, S);
      float4 v = vpos[C];
      float ax = v.x - qx, ay = v.y - qy, az = v.z - qz;
      float ss = fmaf(ax, ax, fmaf(ay, ay, az * az));
      if (ss < 1e-16f) closeMask |= (1ull << C);   // d<1e-8 <=> ss<1e-16
      float ir = rsq_f(ss);
      ux[S] = ax * ir; uy[S] = ay * ir; uz[S] = az * ir; dd[S] = ss * ir;
      VtxS<Q, S + 1>::go(vpos, qx, qy, qz, ux, uy, uz, dd, closeMask);
    }
  }
};

// ---- one face, compile-time compact-slot indices ----
template<int Q, int F, int NT>
__device__ __forceinline__ void face_body(
    const float (&ux)[NT], const float (&uy)[NT], const float (&uz)[NT],
    const float (&dd)[NT], float (&wacc)[NT], int& anyInside)
{
  constexpr unsigned long long M = chunk_vmask(Q);
  constexpr int s0 = slot_of_c(M, FC[F][0]);
  constexpr int s1 = slot_of_c(M, FC[F][1]);
  constexpr int s2 = slot_of_c(M, FC[F][2]);
  float ex = ux[s1] - ux[s2], ey = uy[s1] - uy[s2], ez = uz[s1] - uz[s2];
  float x0 = 0.5f * sqrt_f(fmaf(ex, ex, fmaf(ey, ey, ez * ez)));
  ex = ux[s2] - ux[s0]; ey = uy[s2] - uy[s0]; ez = uz[s2] - uz[s0];
  float x1 = 0.5f * sqrt_f(fmaf(ex, ex, fmaf(ey, ey, ez * ez)));
  ex = ux[s0] - ux[s1]; ey = uy[s0] - uy[s1]; ez = uz[s0] - uz[s1];
  float x2 = 0.5f * sqrt_f(fmaf(ex, ex, fmaf(ey, ey, ez * ez)));
  if (x0 >= 1.f) x0 = 0.99999f;
  if (x1 >= 1.f) x1 = 0.99999f;
  if (x2 >= 1.f) x2 = 0.99999f;
  float cx0 = sqrt_f(fmaxf(fmaf(-x0, x0, 1.f), 0.f));
  float cx1 = sqrt_f(fmaxf(fmaf(-x1, x1, 1.f), 0.f));
  float cx2 = sqrt_f(fmaxf(fmaf(-x2, x2, 1.f), 0.f));
  float th0 = theta_from_x(x0);
  float th1 = theta_from_x(x1);
  float th2 = theta_from_x(x2);
  float hh = 0.5f * ((th0 + th1) + th2);
  if (3.14159265358979f - hh < 1e-4f) anyInside = 1;
  float st0 = 2.f * (x0 * cx0);
  float st1 = 2.f * (x1 * cx1);
  float st2 = 2.f * (x2 * cx2);
  float A1 = x0 * (cx1 * cx2);
  float A2 = x1 * (cx0 * cx2);
  float A3 = x2 * (cx0 * cx1);
  float A4 = x0 * (x1 * x2);
  float sh  = ((A1 + A2) + A3) - A4;     // sin(h)
  float sm0 = ((-A1 + A2) + A3) + A4;    // sin(h-th0)
  float sm1 = ((A1 - A2) + A3) + A4;
  float sm2 = ((A1 + A2) - A3) + A4;
  float twosh = 2.f * sh;
  float c0 = fmaf(twosh * sm0, rcp_f(st1 * st2), -1.f);
  float c1 = fmaf(twosh * sm1, rcp_f(st2 * st0), -1.f);
  float c2 = fmaf(twosh * sm2, rcp_f(st0 * st1), -1.f);
  c0 = fminf(fmaxf(c0, -0.99999f), 0.99999f);
  c1 = fminf(fmaxf(c1, -0.99999f), 0.99999f);
  c2 = fminf(fmaxf(c2, -0.99999f), 0.99999f);
  float det = ux[s0] * fmaf(uy[s1], uz[s2], -(uz[s1] * uy[s2]))
            - uy[s0] * fmaf(ux[s1], uz[s2], -(uz[s1] * ux[s2]))
            + uz[s0] * fmaf(ux[s1], uy[s2], -(uy[s1] * ux[s2]));
  float sg = (det > 0.f) ? 1.f : ((det < 0.f) ? -1.f : 0.f);
  float sn0 = sg * sqrt_f(fmaf(-c0, c0, 1.f));
  float sn1 = sg * sqrt_f(fmaf(-c1, c1, 1.f));
  float sn2 = sg * sqrt_f(fmaf(-c2, c2, 1.f));
  float w0 = fmaf(-c2, th1, fmaf(-c1, th2, th0)) * rcp_f((dd[s0] * st1) * sn2);
  float w1 = fmaf(-c0, th2, fmaf(-c2, th0, th1)) * rcp_f((dd[s1] * st2) * sn0);
  float w2 = fmaf(-c1, th0, fmaf(-c0, th1, th2)) * rcp_f((dd[s2] * st0) * sn1);
  wacc[s0] += w0;
  wacc[s1] += w1;
  wacc[s2] += w2;
}

template<int Q, int K>
struct FaceChainS {
  static constexpr int NT = popcnt_c(chunk_vmask(Q));
  static __device__ __forceinline__ void go(
      const float (&ux)[NT], const float (&uy)[NT], const float (&uz)[NT],
      const float (&dd)[NT], float (&wacc)[NT], int& anyInside) {
    if constexpr (K < CHF) {
      face_body<Q, Q * CHF + K, NT>(ux, uy, uz, dd, wacc, anyInside);
      FaceChainS<Q, K + 1>::go(ux, uy, uz, dd, wacc, anyInside);
    }
  }
};

template<int Q, int S>
struct AddChainS {
  static constexpr unsigned long long M = chunk_vmask(Q);
  static constexpr int NT = popcnt_c(M);
  static __device__ __forceinline__ void go(float* wjLDS, int p,
                                            const float (&wacc)[NT]) {
    if constexpr (S < NT) {
      atomicAdd(&wjLDS[nth_bit_c(M, S) * WST + p], wacc[S]);
      AddChainS<Q, S + 1>::go(wjLDS, p, wacc);
    }
  }
};

template<int Q>
__device__ __forceinline__ void do_chunk(const float4* vpos,
    float qx, float qy, float qz, float* wjLDS, int p,
    int& anyInside, unsigned long long& closeMask)
{
  constexpr int NT = popcnt_c(chunk_vmask(Q));
  float ux[NT], uy[NT], uz[NT], dd[NT];
  float wacc[NT] = {};
  VtxS<Q, 0>::go(vpos, qx, qy, qz, ux, uy, uz, dd, closeMask);
  FaceChainS<Q, 0>::go(ux, uy, uz, dd, wacc, anyInside);
  AddChainS<Q, 0>::go(wjLDS, p, wacc);
}

// cold path: recompute a face at runtime, inside-formula accumulate
__device__ void inside_face_rt(int f, const float4* vpos,
    float qx, float qy, float qz, float* wjLDS, int p)
{
  int f0 = FR[f][0], f1 = FR[f][1], f2 = FR[f][2];
  float4 v0 = vpos[f0], v1 = vpos[f1], v2 = vpos[f2];
  float a0x = v0.x - qx, a0y = v0.y - qy, a0z = v0.z - qz;
  float a1x = v1.x - qx, a1y = v1.y - qy, a1z = v1.z - qz;
  float a2x = v2.x - qx, a2y = v2.y - qy, a2z = v2.z - qz;
  float ss0 = fmaf(a0x, a0x, fmaf(a0y, a0y, a0z * a0z));
  float ss1 = fmaf(a1x, a1x, fmaf(a1y, a1y, a1z * a1z));
  float ss2 = fmaf(a2x, a2x, fmaf(a2y, a2y, a2z * a2z));
  float i0 = rsq_f(ss0), i1 = rsq_f(ss1), i2 = rsq_f(ss2);
  float d0 = ss0 * i0, d1 = ss1 * i1, d2 = ss2 * i2;
  float u0x = a0x * i0, u0y = a0y * i0, u0z = a0z * i0;
  float u1x = a1x * i1, u1y = a1y * i1, u1z = a1z * i1;
  float u2x = a2x * i2, u2y = a2y * i2, u2z = a2z * i2;
  float ex = u1x - u2x, ey = u1y - u2y, ez = u1z - u2z;
  float x0 = 0.5f * sqrt_f(fmaf(ex, ex, fmaf(ey, ey, ez * ez)));
  ex = u2x - u0x; ey = u2y - u0y; ez = u2z - u0z;
  float x1 = 0.5f * sqrt_f(fmaf(ex, ex, fmaf(ey, ey, ez * ez)));
  ex = u0x - u1x; ey = u0y - u1y; ez = u0z - u1z;
  float x2 = 0.5f * sqrt_f(fmaf(ex, ex, fmaf(ey, ey, ez * ez)));
  if (x0 >= 1.f) x0 = 0.99999f;
  if (x1 >= 1.f) x1 = 0.99999f;
  if (x2 >= 1.f) x2 = 0.99999f;
  float th0 = theta_from_x(x0), th1 = theta_from_x(x1), th2 = theta_from_x(x2);
  float hh = 0.5f * ((th0 + th1) + th2);
  if (3.14159265358979f - hh < 1e-4f) {
    float cx0 = sqrt_f(fmaxf(fmaf(-x0, x0, 1.f), 0.f));
    float cx1 = sqrt_f(fmaxf(fmaf(-x1, x1, 1.f), 0.f));
    float cx2 = sqrt_f(fmaxf(fmaf(-x2, x2, 1.f), 0.f));
    atomicAdd(&wjLDS[f0 * WST + p], (2.f * (x0 * cx0) * d2) * d1);
    atomicAdd(&wjLDS[f1 * WST + p], (2.f * (x1 * cx1) * d0) * d2);
    atomicAdd(&wjLDS[f2 * WST + p], (2.f * (x2 * cx2) * d1) * d0);
  }
}

// ---------------- Kernel D: MVC weights + deformed ----------------
__global__ __launch_bounds__(512) void mvc_kernel(
    const float* __restrict__ src,      // (B,3,N)
    const float* __restrict__ cage_t,   // (B,42,3)
    const float* __restrict__ ncage_t,  // (B,42,3)
    float* __restrict__ out_def,        // (B,3,N)
    float* __restrict__ out_w)          // (B,N,42)
{
  __shared__ float4 vpos[NV];
  __shared__ float4 npos[NV];
  __shared__ float wjLDS[NV * WST];
  __shared__ int insideL[PPB];
  __shared__ unsigned int closeL[2 * PPB];
  __shared__ int blkIn;

  int tid = threadIdx.x;
  int p = tid & (PPB - 1);
  int q = tid >> 6;
  int b    = blockIdx.x / (NP / PPB);
  int pblk = blockIdx.x % (NP / PPB);
  int gp   = pblk * PPB + p;

  if (tid < NV) {
    const float* cp = cage_t + (size_t)b * NV * 3 + tid * 3;
    vpos[tid] = make_float4(cp[0], cp[1], cp[2], 0.f);
    const float* np_ = ncage_t + (size_t)b * NV * 3 + tid * 3;
    npos[tid] = make_float4(np_[0], np_[1], np_[2], 0.f);
  }
  for (int i = tid; i < NV * WST; i += 512) wjLDS[i] = 0.f;
  if (tid < PPB) insideL[tid] = 0;
  if (tid < 2 * PPB) closeL[tid] = 0u;
  if (tid == 0) blkIn = 0;
  __syncthreads();

  float qx = src[(size_t)b * 3 * NP + gp];
  float qy = src[(size_t)b * 3 * NP + NP + gp];
  float qz = src[(size_t)b * 3 * NP + 2 * NP + gp];

  int anyInside = 0;
  unsigned long long closeMask = 0ull;

  switch (q) {
    case 0: do_chunk<0>(vpos, qx, qy, qz, wjLDS, p, anyInside, closeMask); break;
    case 1: do_chunk<1>(vpos, qx, qy, qz, wjLDS, p, anyInside, closeMask); break;
    case 2: do_chunk<2>(vpos, qx, qy, qz, wjLDS, p, anyInside, closeMask); break;
    case 3: do_chunk<3>(vpos, qx, qy, qz, wjLDS, p, anyInside, closeMask); break;
    case 4: do_chunk<4>(vpos, qx, qy, qz, wjLDS, p, anyInside, closeMask); break;
    case 5: do_chunk<5>(vpos, qx, qy, qz, wjLDS, p, anyInside, closeMask); break;
    case 6: do_chunk<6>(vpos, qx, qy, qz, wjLDS, p, anyInside, closeMask); break;
    default: do_chunk<7>(vpos, qx, qy, qz, wjLDS, p, anyInside, closeMask); break;
  }

  if (anyInside) { insideL[p] = 1; blkIn = 1; }   // benign same-value races
  if (closeMask) {
    atomicOr(&closeL[p], (unsigned int)closeMask);
    atomicOr(&closeL[PPB + p], (unsigned int)(closeMask >> 32));
  }
  __syncthreads();

  if (blkIn) {   // cold: exact `where(inside, ...)` semantics
    if (tid < PPB && insideL[tid])
      for (int c = 0; c < NV; c++) wjLDS[c * WST + tid] = 0.f;
    __syncthreads();
    if (insideL[p])
      for (int f = q * CHF; f < q * CHF + CHF; f++)
        inside_face_rt(f, vpos, qx, qy, qz, wjLDS, p);
    __syncthreads();
  }
  __syncthreads();

  if (tid < PPB) {
    unsigned long long mCl =
        (unsigned long long)closeL[tid] |
        ((unsigned long long)closeL[PPB + tid] << 32);
    float sum = 0.f;
    for (int c = 0; c < NV; c++) {
      float v = wjLDS[c * WST + tid];
      if (mCl) { v = ((mCl >> c) & 1ull) ? 1.f : 0.f; wjLDS[c * WST + tid] = v; }
      sum += v;
    }
    if (sum == 0.f) sum = 1.f;
    float inv = rcp_f(sum);
    float ax = 0.f, ay = 0.f, az = 0.f;
    for (int c = 0; c < NV; c++) {
      float w = wjLDS[c * WST + tid] * inv;
      wjLDS[c * WST + tid] = w;
      float4 n = npos[c];
      ax = fmaf(w, n.x, ax);
      ay = fmaf(w, n.y, ay);
      az = fmaf(w, n.z, az);
    }
    int gpp = pblk * PPB + tid;
    out_def[(size_t)b * 3 * NP + gpp]          = ax;
    out_def[(size_t)b * 3 * NP + NP + gpp]     = ay;
    out_def[(size_t)b * 3 * NP + 2 * NP + gpp] = az;
  }
  __syncthreads();

  float* wbase = out_w + ((size_t)b * NP + pblk * PPB) * NV;
  for (int idx = tid; idx < PPB * NV; idx += 512) {
    int pp = idx / NV;
    int c  = idx - pp * NV;
    wbase[idx] = wjLDS[c * WST + pp];
  }
}

// ---------------- Kernel A: optimize_cage (round-3 proven) ----------------
__global__ __launch_bounds__(256) void cage_opt_kernel(
    const float* __restrict__ tmpl,   // (1,3,42)
    const float* __restrict__ src,    // (B,3,N)
    float* __restrict__ cage)         // (B,3,42) scratch
{
  __shared__ float red[8];
  int b = blockIdx.x / NV;
  int v = blockIdx.x % NV;
  const float* sp = src + (size_t)b * 3 * NP;
  float cx = tmpl[v], cy = tmpl[NV + v], cz = tmpl[2 * NV + v];
  int k = 0;
  while (true) {
    float m = 3.4e38f;
    for (int i = threadIdx.x; i < NP; i += 256) {
      float dx = __fsub_rn(cx, sp[i]);
      float dy = __fsub_rn(cy, sp[NP + i]);
      float dz = __fsub_rn(cz, sp[2 * NP + i]);
      float ss = __fadd_rn(__fadd_rn(__fmul_rn(dx, dx), __fmul_rn(dy, dy)),
                           __fmul_rn(dz, dz));
      m = fminf(m, ss);
    }
    #pragma unroll
    for (int off = 32; off > 0; off >>= 1)
      m = fminf(m, __shfl_down(m, off, 64));
    int wid = threadIdx.x >> 6;
    __syncthreads();
    if ((threadIdx.x & 63) == 0) red[wid] = m;
    __syncthreads();
    if (threadIdx.x == 0) {
      float mm = fminf(fminf(red[0], red[1]), fminf(red[2], red[3]));
      red[4] = sqrtf(mm);
    }
    __syncthreads();
    float mind = red[4];
    if (mind > 0.4f && k < 100) {
      cx = __fsub_rn(cx, __fmul_rn(0.01f, cx));
      cy = __fsub_rn(cy, __fmul_rn(0.01f, cy));
      cz = __fsub_rn(cz, __fmul_rn(0.01f, cz));
      k++;
    } else {
      break;
    }
  }
  if (threadIdx.x == 0) {
    cage[(size_t)b * 3 * NV + v]          = cx;
    cage[(size_t)b * 3 * NV + NV + v]     = cy;
    cage[(size_t)b * 3 * NV + 2 * NV + v] = cz;
  }
}

// ---------------- MLP: split-K linear (round-3 proven) ----------------
__global__ __launch_bounds__(256) void linear_splitk(
    const float* __restrict__ in0, const float* __restrict__ in1,
    const float* __restrict__ W, const float* __restrict__ bias,
    float* __restrict__ out, int FI, int FO, int relu)
{
  __shared__ float sIn[512];
  __shared__ float part[4][64];
  int bb = blockIdx.y;
  int tid = threadIdx.x;
  for (int i = tid; i < FI; i += 256) {
    float v;
    if (in1) v = (i < FEAT) ? in0[(size_t)bb * FEAT + i]
                            : in1[(size_t)bb * FEAT + i - FEAT];
    else     v = in0[(size_t)bb * FI + i];
    sIn[i] = v;
  }
  __syncthreads();
  int o = blockIdx.x * 64 + (tid & 63);
  int kk = tid >> 6;               // wave-uniform k chunk
  int seg = FI >> 2;
  float acc = 0.f;
  const float* wp = W + o;
  #pragma unroll 4
  for (int i = kk * seg; i < (kk + 1) * seg; i++)
    acc = fmaf(sIn[i], wp[(size_t)i * FO], acc);
  part[kk][tid & 63] = acc;
  __syncthreads();
  if (tid < 64) {
    float r = ((part[0][tid] + part[1][tid]) + (part[2][tid] + part[3][tid]))
              + bias[o];
    out[(size_t)bb * FO + o] = relu ? fmaxf(r, 0.f) : r;
  }
}

// ---------------- L4 + cage finalize (round-3 proven) ----------------
__global__ __launch_bounds__(128) void l4_finalize_kernel(
    const float* __restrict__ h3,     // (B,256)
    const float* __restrict__ W4, const float* __restrict__ b4,
    const float* __restrict__ cage,   // (B,3,42) scratch
    float* __restrict__ out_io,       // (B,126)
    float* __restrict__ cage_t,       // (B,42,3)
    float* __restrict__ ncage_t)      // (B,42,3)
{
  __shared__ float sIn[256];
  int bb = blockIdx.x;
  int tid = threadIdx.x;
  sIn[tid] = h3[(size_t)bb * 256 + tid];
  sIn[tid + 128] = h3[(size_t)bb * 256 + tid + 128];
  __syncthreads();
  if (tid < 126) {
    float acc = b4[tid];
    const float* wp = W4 + tid;
    #pragma unroll 4
    for (int i = 0; i < 256; i++) acc = fmaf(sIn[i], wp[(size_t)i * 126], acc);
    out_io[(size_t)bb * 126 + tid] = acc;
    float c  = cage[(size_t)bb * 126 + tid];
    float nc = c + acc;
    int d = tid / NV, v = tid - d * NV;
    cage_t[(size_t)bb * NV * 3 + v * 3 + d]  = c;
    ncage_t[(size_t)bb * NV * 3 + v * 3 + d] = nc;
  }
}

extern "C" void kernel_launch(void* const* d_in, const int* in_sizes, int n_in,
                              void* d_out, int out_size, void* d_ws, size_t ws_size,
                              hipStream_t stream) {
  (void)in_sizes; (void)n_in; (void)out_size; (void)d_ws; (void)ws_size;
  const float* src   = (const float*)d_in[0];
  const float* sf    = (const float*)d_in[2];
  const float* tf    = (const float*)d_in[3];
  const float* tmpl  = (const float*)d_in[4];
  const float* W1 = (const float*)d_in[6];  const float* b1 = (const float*)d_in[7];
  const float* W2 = (const float*)d_in[8];  const float* b2 = (const float*)d_in[9];
  const float* W3 = (const float*)d_in[10]; const float* b3 = (const float*)d_in[11];
  const float* W4 = (const float*)d_in[12]; const float* b4 = (const float*)d_in[13];

  float* out = (float*)d_out;
  float* out_cage_t  = out;                 // (16,42,3)   2016
  float* out_ncage_t = out + 2016;          // (16,42,3)   2016
  float* out_def     = out + 4032;          // (16,3,8192) 393216
  float* out_w       = out + 397248;        // (16,8192,42) 5505024
  float* out_io      = out + 5902272;       // (16,126)    2016

  // scratch carved out of the weights region (fully overwritten by mvc_kernel)
  float* s_cage = out_w;           // 2016
  float* s_h1   = out_w + 2016;    // 8192
  float* s_h2   = out_w + 10208;   // 8192
  float* s_h3   = out_w + 18400;   // 4096

  cage_opt_kernel<<<dim3(BB * NV), dim3(256), 0, stream>>>(tmpl, src, s_cage);
  linear_splitk<<<dim3(8, BB), dim3(256), 0, stream>>>(sf, tf, W1, b1, s_h1, 512, 512, 1);
  linear_splitk<<<dim3(8, BB), dim3(256), 0, stream>>>(s_h1, nullptr, W2, b2, s_h2, 512, 512, 1);
  linear_splitk<<<dim3(4, BB), dim3(256), 0, stream>>>(s_h2, nullptr, W3, b3, s_h3, 512, 256, 1);
  l4_finalize_kernel<<<dim3(BB), dim3(128), 0, stream>>>(
      s_h3, W4, b4, s_cage, out_io, out_cage_t, out_ncage_t);
  mvc_kernel<<<dim3(BB * (NP / PPB)), dim3(512), 0, stream>>>(
      src, out_cage_t, out_ncage_t, out_def, out_w);
}

// Round 6
// 239.454 us; speedup vs baseline: 1.1494x; 1.1494x over previous
//
#include <hip/hip_runtime.h>
#include <math.h>

#define BB 16
#define NP 8192
#define NV 42
#define NF 80
#define FEAT 256
#define PPB 64           // points per block (mvc)
#define QF  20           // faces per quarter-thread
#define WJS 65           // padded LDS stride for wj (65%32==1 -> transposed read conflict-free)

__device__ __forceinline__ float rcp_f(float x)  { return __builtin_amdgcn_rcpf(x); }
__device__ __forceinline__ float rsq_f(float x)  { return __builtin_amdgcn_rsqf(x); }
__device__ __forceinline__ float sqrt_f(float x) { return __builtin_amdgcn_sqrtf(x); }

// theta = 2*asin(x), x in [0,1). Branchless, |err|~1e-5. (validated r2-r5)
__device__ __forceinline__ float theta_from_x(float x) {
  bool big = x > 0.5f;
  float z = big ? fmaf(-0.5f, x, 0.5f) : x * x;
  float s = big ? sqrt_f(z) : x;
  float P = fmaf(z, 0.022371875f, 0.030381944f);
  P = fmaf(z, P, 0.044642857f);
  P = fmaf(z, P, 0.075f);
  P = fmaf(z, P, 0.16666667f);
  float r = fmaf(s * z, P, s);
  return big ? fmaf(-4.f, r, 3.14159265358979f) : 2.f * r;
}

// cold path: recompute a face at runtime, inside-formula accumulate
__device__ __attribute__((noinline)) void inside_face_rt(
    int f0, int f1, int f2, const float4* vpos,
    float qx, float qy, float qz, float* wj, int p)
{
  float4 v0 = vpos[f0], v1 = vpos[f1], v2 = vpos[f2];
  float a0x = v0.x - qx, a0y = v0.y - qy, a0z = v0.z - qz;
  float a1x = v1.x - qx, a1y = v1.y - qy, a1z = v1.z - qz;
  float a2x = v2.x - qx, a2y = v2.y - qy, a2z = v2.z - qz;
  float ss0 = fmaf(a0x, a0x, fmaf(a0y, a0y, a0z * a0z));
  float ss1 = fmaf(a1x, a1x, fmaf(a1y, a1y, a1z * a1z));
  float ss2 = fmaf(a2x, a2x, fmaf(a2y, a2y, a2z * a2z));
  float i0 = rsq_f(ss0), i1 = rsq_f(ss1), i2 = rsq_f(ss2);
  float d0 = ss0 * i0, d1 = ss1 * i1, d2 = ss2 * i2;
  float u0x = a0x * i0, u0y = a0y * i0, u0z = a0z * i0;
  float u1x = a1x * i1, u1y = a1y * i1, u1z = a1z * i1;
  float u2x = a2x * i2, u2y = a2y * i2, u2z = a2z * i2;
  float ex = u1x - u2x, ey = u1y - u2y, ez = u1z - u2z;
  float x0 = 0.5f * sqrt_f(fmaf(ex, ex, fmaf(ey, ey, ez * ez)));
  ex = u2x - u0x; ey = u2y - u0y; ez = u2z - u0z;
  float x1 = 0.5f * sqrt_f(fmaf(ex, ex, fmaf(ey, ey, ez * ez)));
  ex = u0x - u1x; ey = u0y - u1y; ez = u0z - u1z;
  float x2 = 0.5f * sqrt_f(fmaf(ex, ex, fmaf(ey, ey, ez * ez)));
  if (x0 >= 1.f) x0 = 0.99999f;
  if (x1 >= 1.f) x1 = 0.99999f;
  if (x2 >= 1.f) x2 = 0.99999f;
  float th0 = theta_from_x(x0), th1 = theta_from_x(x1), th2 = theta_from_x(x2);
  float hh = 0.5f * ((th0 + th1) + th2);
  if (3.14159265358979f - hh < 1e-4f) {
    float cx0 = sqrt_f(fmaxf(fmaf(-x0, x0, 1.f), 0.f));
    float cx1 = sqrt_f(fmaxf(fmaf(-x1, x1, 1.f), 0.f));
    float cx2 = sqrt_f(fmaxf(fmaf(-x2, x2, 1.f), 0.f));
    atomicAdd(&wj[f0 * WJS + p], (2.f * (x0 * cx0) * d2) * d1);
    atomicAdd(&wj[f1 * WJS + p], (2.f * (x1 * cx1) * d0) * d2);
    atomicAdd(&wj[f2 * WJS + p], (2.f * (x2 * cx2) * d1) * d0);
  }
}

// ---------------- Kernel D: MVC weights + deformed ----------------
// 256 threads = 4 waves; wave q does faces [q*20,(q+1)*20) of point p=tid&63.
// Shared runtime loop (one code region for all waves -> no I$ thrash).
__global__ __launch_bounds__(256) void mvc_kernel(
    const float* __restrict__ src,      // (B,3,N)
    const float* __restrict__ cage_t,   // (B,42,3)
    const float* __restrict__ ncage_t,  // (B,42,3)
    const int* __restrict__ faces,      // (80,3)
    float* __restrict__ out_def,        // (B,3,N)
    float* __restrict__ out_w)          // (B,N,42)
{
  __shared__ float4 vpos[NV];
  __shared__ float4 npos[NV];
  __shared__ int fidp[NF];
  __shared__ float wj[NV * WJS];
  __shared__ float spart[4][PPB];
  __shared__ float dxp[4][PPB], dyp[4][PPB], dzp[4][PPB];
  __shared__ float invL[PPB];
  __shared__ unsigned int closeLo[PPB], closeHi[PPB];
  __shared__ int insideL[PPB];
  __shared__ int blkIn;

  const float PI_F = 3.14159265358979323846f;
  int tid = threadIdx.x;
  int p = tid & (PPB - 1);
  int q = tid >> 6;
  int b    = blockIdx.x / (NP / PPB);
  int pblk = blockIdx.x % (NP / PPB);
  int gp   = pblk * PPB + p;

  if (tid < NV) {
    const float* cp = cage_t + (size_t)b * NV * 3 + tid * 3;
    vpos[tid] = make_float4(cp[0], cp[1], cp[2], 0.f);
    const float* np_ = ncage_t + (size_t)b * NV * 3 + tid * 3;
    npos[tid] = make_float4(np_[0], np_[1], np_[2], 0.f);
  }
  if (tid < NF) {
    int f0 = faces[3 * tid], f1 = faces[3 * tid + 1], f2 = faces[3 * tid + 2];
    fidp[tid] = f0 | (f1 << 6) | (f2 << 12);
  }
  for (int i = tid; i < NV * WJS; i += 256) wj[i] = 0.f;
  if (tid < PPB) { insideL[tid] = 0; closeLo[tid] = 0u; closeHi[tid] = 0u; }
  if (tid == 0) blkIn = 0;
  __syncthreads();

  float qx = src[(size_t)b * 3 * NP + gp];
  float qy = src[(size_t)b * 3 * NP + NP + gp];
  float qz = src[(size_t)b * 3 * NP + 2 * NP + gp];

  int anyInside = 0;
  unsigned long long closeMask = 0ull;

  #pragma unroll 1
  for (int i = q * QF; i < q * QF + QF; i++) {
    int pk = fidp[i];
    int f0 = pk & 63, f1 = (pk >> 6) & 63, f2 = pk >> 12;
    float4 v0 = vpos[f0], v1 = vpos[f1], v2 = vpos[f2];
    float a0x = v0.x - qx, a0y = v0.y - qy, a0z = v0.z - qz;
    float a1x = v1.x - qx, a1y = v1.y - qy, a1z = v1.z - qz;
    float a2x = v2.x - qx, a2y = v2.y - qy, a2z = v2.z - qz;
    float ss0 = fmaf(a0x, a0x, fmaf(a0y, a0y, a0z * a0z));
    float ss1 = fmaf(a1x, a1x, fmaf(a1y, a1y, a1z * a1z));
    float ss2 = fmaf(a2x, a2x, fmaf(a2y, a2y, a2z * a2z));
    if (ss0 < 1e-16f) closeMask |= (1ull << f0);
    if (ss1 < 1e-16f) closeMask |= (1ull << f1);
    if (ss2 < 1e-16f) closeMask |= (1ull << f2);
    float i0 = rsq_f(ss0), i1 = rsq_f(ss1), i2 = rsq_f(ss2);
    float d0 = ss0 * i0, d1 = ss1 * i1, d2 = ss2 * i2;
    float u0x = a0x * i0, u0y = a0y * i0, u0z = a0z * i0;
    float u1x = a1x * i1, u1y = a1y * i1, u1z = a1z * i1;
    float u2x = a2x * i2, u2y = a2y * i2, u2z = a2z * i2;
    float ex = u1x - u2x, ey = u1y - u2y, ez = u1z - u2z;
    float x0 = 0.5f * sqrt_f(fmaf(ex, ex, fmaf(ey, ey, ez * ez)));
    ex = u2x - u0x; ey = u2y - u0y; ez = u2z - u0z;
    float x1 = 0.5f * sqrt_f(fmaf(ex, ex, fmaf(ey, ey, ez * ez)));
    ex = u0x - u1x; ey = u0y - u1y; ez = u0z - u1z;
    float x2 = 0.5f * sqrt_f(fmaf(ex, ex, fmaf(ey, ey, ez * ez)));
    if (x0 >= 1.f) x0 = 0.99999f;
    if (x1 >= 1.f) x1 = 0.99999f;
    if (x2 >= 1.f) x2 = 0.99999f;
    float cx0 = sqrt_f(fmaxf(fmaf(-x0, x0, 1.f), 0.f));
    float cx1 = sqrt_f(fmaxf(fmaf(-x1, x1, 1.f), 0.f));
    float cx2 = sqrt_f(fmaxf(fmaf(-x2, x2, 1.f), 0.f));
    float th0 = theta_from_x(x0);
    float th1 = theta_from_x(x1);
    float th2 = theta_from_x(x2);
    float hh = 0.5f * ((th0 + th1) + th2);
    if (PI_F - hh < 1e-4f) anyInside = 1;
    float st0 = 2.f * (x0 * cx0);
    float st1 = 2.f * (x1 * cx1);
    float st2 = 2.f * (x2 * cx2);
    float A1 = x0 * (cx1 * cx2);
    float A2 = x1 * (cx0 * cx2);
    float A3 = x2 * (cx0 * cx1);
    float A4 = x0 * (x1 * x2);
    float sh  = ((A1 + A2) + A3) - A4;     // sin(h)
    float sm0 = ((-A1 + A2) + A3) + A4;    // sin(h-th0)
    float sm1 = ((A1 - A2) + A3) + A4;
    float sm2 = ((A1 + A2) - A3) + A4;
    float twosh = 2.f * sh;
    float c0 = fmaf(twosh * sm0, rcp_f(st1 * st2), -1.f);
    float c1 = fmaf(twosh * sm1, rcp_f(st2 * st0), -1.f);
    float c2 = fmaf(twosh * sm2, rcp_f(st0 * st1), -1.f);
    c0 = fminf(fmaxf(c0, -0.99999f), 0.99999f);
    c1 = fminf(fmaxf(c1, -0.99999f), 0.99999f);
    c2 = fminf(fmaxf(c2, -0.99999f), 0.99999f);
    float det = u0x * fmaf(u1y, u2z, -(u1z * u2y))
              - u0y * fmaf(u1x, u2z, -(u1z * u2x))
              + u0z * fmaf(u1x, u2y, -(u1y * u2x));
    float sg = (det > 0.f) ? 1.f : ((det < 0.f) ? -1.f : 0.f);
    float sn0 = sg * sqrt_f(fmaf(-c0, c0, 1.f));
    float sn1 = sg * sqrt_f(fmaf(-c1, c1, 1.f));
    float sn2 = sg * sqrt_f(fmaf(-c2, c2, 1.f));
    float w0 = fmaf(-c2, th1, fmaf(-c1, th2, th0)) * rcp_f((d0 * st1) * sn2);
    float w1 = fmaf(-c0, th2, fmaf(-c2, th0, th1)) * rcp_f((d1 * st2) * sn0);
    float w2 = fmaf(-c1, th0, fmaf(-c0, th1, th2)) * rcp_f((d2 * st0) * sn1);
    atomicAdd(&wj[f0 * WJS + p], w0);
    atomicAdd(&wj[f1 * WJS + p], w1);
    atomicAdd(&wj[f2 * WJS + p], w2);
  }

  if (anyInside) { insideL[p] = 1; blkIn = 1; }   // benign same-value races
  if (closeMask) {
    atomicOr(&closeLo[p], (unsigned int)closeMask);
    atomicOr(&closeHi[p], (unsigned int)(closeMask >> 32));
  }
  __syncthreads();

  if (blkIn) {   // cold: exact `where(inside, ...)` semantics
    if (tid < PPB && insideL[tid])
      for (int c = 0; c < NV; c++) wj[c * WJS + tid] = 0.f;
    __syncthreads();
    if (insideL[p]) {
      for (int i = q * QF; i < q * QF + QF; i++) {
        int pk = fidp[i];
        inside_face_rt(pk & 63, (pk >> 6) & 63, pk >> 12,
                       vpos, qx, qy, qz, wj, p);
      }
    }
    __syncthreads();
  }

  // parallel partial sums (4 waves, stride-4 interleave over c)
  {
    float ps = 0.f;
    for (int c = q; c < NV; c += 4) ps += wj[c * WJS + p];
    spart[q][p] = ps;
  }
  __syncthreads();
  if (tid < PPB) {
    unsigned long long mCl =
        (unsigned long long)closeLo[tid] |
        ((unsigned long long)closeHi[tid] << 32);
    float sum;
    if (mCl) {   // cold: query coincides with cage vertex
      for (int c = 0; c < NV; c++)
        wj[c * WJS + tid] = ((mCl >> c) & 1ull) ? 1.f : 0.f;
      sum = (float)__popcll(mCl);
    } else {
      sum = (spart[0][tid] + spart[1][tid]) + (spart[2][tid] + spart[3][tid]);
    }
    if (sum == 0.f) sum = 1.f;
    invL[tid] = rcp_f(sum);
  }
  __syncthreads();
  {
    float inv = invL[p];
    float ax = 0.f, ay = 0.f, az = 0.f;
    for (int c = q; c < NV; c += 4) {
      float w = wj[c * WJS + p] * inv;
      wj[c * WJS + p] = w;
      float4 n = npos[c];
      ax = fmaf(w, n.x, ax);
      ay = fmaf(w, n.y, ay);
      az = fmaf(w, n.z, az);
    }
    dxp[q][p] = ax; dyp[q][p] = ay; dzp[q][p] = az;
  }
  __syncthreads();
  if (tid < PPB) {
    float ax = (dxp[0][tid] + dxp[1][tid]) + (dxp[2][tid] + dxp[3][tid]);
    float ay = (dyp[0][tid] + dyp[1][tid]) + (dyp[2][tid] + dyp[3][tid]);
    float az = (dzp[0][tid] + dzp[1][tid]) + (dzp[2][tid] + dzp[3][tid]);
    int gpp = pblk * PPB + tid;
    out_def[(size_t)b * 3 * NP + gpp]          = ax;
    out_def[(size_t)b * 3 * NP + NP + gpp]     = ay;
    out_def[(size_t)b * 3 * NP + 2 * NP + gpp] = az;
  }
  __syncthreads();

  // coalesced weight write: (PPB x 42) contiguous; wj stride 65 -> conflict-free
  float* wbase = out_w + ((size_t)b * NP + pblk * PPB) * NV;
  for (int idx = tid; idx < PPB * NV; idx += 256) {
    int pp = idx / NV;
    int c  = idx - pp * NV;
    wbase[idx] = wj[c * WJS + pp];
  }
}

// ---------------- shared split-K linear body (round-3 proven) ----------------
__device__ __forceinline__ void splitk_body(
    const float* in0, const float* in1,
    const float* W, const float* bias, float* out,
    int FI, int FO, int relu, int ox, int bb, int tid,
    float* sIn, float (*part)[64])
{
  for (int i = tid; i < FI; i += 256) {
    float v;
    if (in1) v = (i < FEAT) ? in0[(size_t)bb * FEAT + i]
                            : in1[(size_t)bb * FEAT + i - FEAT];
    else     v = in0[(size_t)bb * FI + i];
    sIn[i] = v;
  }
  __syncthreads();
  int o = ox * 64 + (tid & 63);
  int kk = tid >> 6;
  int seg = FI >> 2;
  float acc = 0.f;
  const float* wp = W + o;
  #pragma unroll 4
  for (int i = kk * seg; i < (kk + 1) * seg; i++)
    acc = fmaf(sIn[i], wp[(size_t)i * FO], acc);
  part[kk][tid & 63] = acc;
  __syncthreads();
  if (tid < 64) {
    float r = ((part[0][tid] + part[1][tid]) + (part[2][tid] + part[3][tid]))
              + bias[o];
    out[(size_t)bb * FO + o] = relu ? fmaxf(r, 0.f) : r;
  }
}

// ---------------- Kernel A: cage_opt (blocks<672) + L1 split-K (672..799) ----
__global__ __launch_bounds__(256) void cage_l1_kernel(
    const float* __restrict__ tmpl, const float* __restrict__ src,
    const float* __restrict__ sf, const float* __restrict__ tf,
    const float* __restrict__ W1, const float* __restrict__ b1,
    float* __restrict__ cage, float* __restrict__ h1)
{
  __shared__ float red[8];
  __shared__ float sIn[512];
  __shared__ float part[4][64];
  int tid = threadIdx.x;

  if (blockIdx.x < BB * NV) {
    int b = blockIdx.x / NV;
    int v = blockIdx.x % NV;
    const float* sp = src + (size_t)b * 3 * NP;
    float cx = tmpl[v], cy = tmpl[NV + v], cz = tmpl[2 * NV + v];
    int k = 0;
    while (true) {
      float m = 3.4e38f;
      for (int i = tid; i < NP; i += 256) {
        float dx = __fsub_rn(cx, sp[i]);
        float dy = __fsub_rn(cy, sp[NP + i]);
        float dz = __fsub_rn(cz, sp[2 * NP + i]);
        float ss = __fadd_rn(__fadd_rn(__fmul_rn(dx, dx), __fmul_rn(dy, dy)),
                             __fmul_rn(dz, dz));
        m = fminf(m, ss);
      }
      #pragma unroll
      for (int off = 32; off > 0; off >>= 1)
        m = fminf(m, __shfl_down(m, off, 64));
      int wid = tid >> 6;
      __syncthreads();
      if ((tid & 63) == 0) red[wid] = m;
      __syncthreads();
      if (tid == 0) {
        float mm = fminf(fminf(red[0], red[1]), fminf(red[2], red[3]));
        red[4] = sqrtf(mm);
      }
      __syncthreads();
      float mind = red[4];
      if (mind > 0.4f && k < 100) {
        cx = __fsub_rn(cx, __fmul_rn(0.01f, cx));
        cy = __fsub_rn(cy, __fmul_rn(0.01f, cy));
        cz = __fsub_rn(cz, __fmul_rn(0.01f, cz));
        k++;
      } else {
        break;
      }
    }
    if (tid == 0) {
      cage[(size_t)b * 3 * NV + v]          = cx;
      cage[(size_t)b * 3 * NV + NV + v]     = cy;
      cage[(size_t)b * 3 * NV + 2 * NV + v] = cz;
    }
  } else {
    int idx = blockIdx.x - BB * NV;   // 0..127
    splitk_body(sf, tf, W1, b1, h1, 512, 512, 1, idx & 7, idx >> 3,
                tid, sIn, part);
  }
}

// ---------------- standalone split-K linear (round-3 proven) ----------------
__global__ __launch_bounds__(256) void linear_splitk(
    const float* __restrict__ in0, const float* __restrict__ in1,
    const float* __restrict__ W, const float* __restrict__ bias,
    float* __restrict__ out, int FI, int FO, int relu)
{
  __shared__ float sIn[512];
  __shared__ float part[4][64];
  splitk_body(in0, in1, W, bias, out, FI, FO, relu,
              blockIdx.x, blockIdx.y, threadIdx.x, sIn, part);
}

// ---------------- L4 + cage finalize (round-3 proven) ----------------
__global__ __launch_bounds__(128) void l4_finalize_kernel(
    const float* __restrict__ h3,
    const float* __restrict__ W4, const float* __restrict__ b4,
    const float* __restrict__ cage,
    float* __restrict__ out_io,
    float* __restrict__ cage_t,
    float* __restrict__ ncage_t)
{
  __shared__ float sIn[256];
  int bb = blockIdx.x;
  int tid = threadIdx.x;
  sIn[tid] = h3[(size_t)bb * 256 + tid];
  sIn[tid + 128] = h3[(size_t)bb * 256 + tid + 128];
  __syncthreads();
  if (tid < 126) {
    float acc = b4[tid];
    const float* wp = W4 + tid;
    #pragma unroll 4
    for (int i = 0; i < 256; i++) acc = fmaf(sIn[i], wp[(size_t)i * 126], acc);
    out_io[(size_t)bb * 126 + tid] = acc;
    float c  = cage[(size_t)bb * 126 + tid];
    float nc = c + acc;
    int d = tid / NV, v = tid - d * NV;
    cage_t[(size_t)bb * NV * 3 + v * 3 + d]  = c;
    ncage_t[(size_t)bb * NV * 3 + v * 3 + d] = nc;
  }
}

extern "C" void kernel_launch(void* const* d_in, const int* in_sizes, int n_in,
                              void* d_out, int out_size, void* d_ws, size_t ws_size,
                              hipStream_t stream) {
  (void)in_sizes; (void)n_in; (void)out_size; (void)d_ws; (void)ws_size;
  const float* src   = (const float*)d_in[0];
  const float* sf    = (const float*)d_in[2];
  const float* tf    = (const float*)d_in[3];
  const float* tmpl  = (const float*)d_in[4];
  const int*   faces = (const int*)d_in[5];
  const float* W1 = (const float*)d_in[6];  const float* b1 = (const float*)d_in[7];
  const float* W2 = (const float*)d_in[8];  const float* b2 = (const float*)d_in[9];
  const float* W3 = (const float*)d_in[10]; const float* b3 = (const float*)d_in[11];
  const float* W4 = (const float*)d_in[12]; const float* b4 = (const float*)d_in[13];

  float* out = (float*)d_out;
  float* out_cage_t  = out;                 // (16,42,3)   2016
  float* out_ncage_t = out + 2016;          // (16,42,3)   2016
  float* out_def     = out + 4032;          // (16,3,8192) 393216
  float* out_w       = out + 397248;        // (16,8192,42) 5505024
  float* out_io      = out + 5902272;       // (16,126)    2016

  // scratch carved out of the weights region (fully overwritten by mvc_kernel)
  float* s_cage = out_w;           // 2016
  float* s_h1   = out_w + 2016;    // 8192
  float* s_h2   = out_w + 10208;   // 8192
  float* s_h3   = out_w + 18400;   // 4096

  cage_l1_kernel<<<dim3(BB * NV + 128), dim3(256), 0, stream>>>(
      tmpl, src, sf, tf, W1, b1, s_cage, s_h1);
  linear_splitk<<<dim3(8, BB), dim3(256), 0, stream>>>(s_h1, nullptr, W2, b2, s_h2, 512, 512, 1);
  linear_splitk<<<dim3(4, BB), dim3(256), 0, stream>>>(s_h2, nullptr, W3, b3, s_h3, 512, 256, 1);
  l4_finalize_kernel<<<dim3(BB), dim3(128), 0, stream>>>(
      s_h3, W4, b4, s_cage, out_io, out_cage_t, out_ncage_t);
  mvc_kernel<<<dim3(BB * (NP / PPB)), dim3(256), 0, stream>>>(
      src, out_cage_t, out_ncage_t, faces, out_def, out_w);
}

// Round 8
// 165.074 us; speedup vs baseline: 1.6673x; 1.4506x over previous
//
#include <hip/hip_runtime.h>
#include <math.h>

#define BB 16
#define NP 8192
#define NV 42
#define NF 80
#define FEAT 256
#define PPB 64           // points per block (mvc)
#define FH  40           // faces per half-wave
#define WJS 65           // padded LDS stride (65%32==1 -> transposed epilogue conflict-free)

__device__ __forceinline__ float rcp_f(float x)  { return __builtin_amdgcn_rcpf(x); }
__device__ __forceinline__ float rsq_f(float x)  { return __builtin_amdgcn_rsqf(x); }
__device__ __forceinline__ float sqrt_f(float x) { return __builtin_amdgcn_sqrtf(x); }

// theta = 2*asin(x), x in [0,1). Branchless, |err|~1e-5. (validated r2-r6)
__device__ __forceinline__ float theta_from_x(float x) {
  bool big = x > 0.5f;
  float z = big ? fmaf(-0.5f, x, 0.5f) : x * x;
  float s = big ? sqrt_f(z) : x;
  float P = fmaf(z, 0.022371875f, 0.030381944f);
  P = fmaf(z, P, 0.044642857f);
  P = fmaf(z, P, 0.075f);
  P = fmaf(z, P, 0.16666667f);
  float r = fmaf(s * z, P, s);
  return big ? fmaf(-4.f, r, 3.14159265358979f) : 2.f * r;
}

// cold path: runtime face recompute, inside-formula accumulate into private region
// (validated r3/r6 math: edge-subtraction chord lengths)
__device__ __attribute__((noinline)) void inside_face_rt(
    int f0, int f1, int f2, const float4* vpos,
    float qx, float qy, float qz, float* wjh)   // wjh = &wj[hf*NV*WJS + p]
{
  float4 v0 = vpos[f0], v1 = vpos[f1], v2 = vpos[f2];
  float a0x = v0.x - qx, a0y = v0.y - qy, a0z = v0.z - qz;
  float a1x = v1.x - qx, a1y = v1.y - qy, a1z = v1.z - qz;
  float a2x = v2.x - qx, a2y = v2.y - qy, a2z = v2.z - qz;
  float ss0 = fmaf(a0x, a0x, fmaf(a0y, a0y, a0z * a0z));
  float ss1 = fmaf(a1x, a1x, fmaf(a1y, a1y, a1z * a1z));
  float ss2 = fmaf(a2x, a2x, fmaf(a2y, a2y, a2z * a2z));
  float i0 = rsq_f(ss0), i1 = rsq_f(ss1), i2 = rsq_f(ss2);
  float d0 = ss0 * i0, d1 = ss1 * i1, d2 = ss2 * i2;
  float u0x = a0x * i0, u0y = a0y * i0, u0z = a0z * i0;
  float u1x = a1x * i1, u1y = a1y * i1, u1z = a1z * i1;
  float u2x = a2x * i2, u2y = a2y * i2, u2z = a2z * i2;
  float ex = u1x - u2x, ey = u1y - u2y, ez = u1z - u2z;
  float x0 = 0.5f * sqrt_f(fmaf(ex, ex, fmaf(ey, ey, ez * ez)));
  ex = u2x - u0x; ey = u2y - u0y; ez = u2z - u0z;
  float x1 = 0.5f * sqrt_f(fmaf(ex, ex, fmaf(ey, ey, ez * ez)));
  ex = u0x - u1x; ey = u0y - u1y; ez = u0z - u1z;
  float x2 = 0.5f * sqrt_f(fmaf(ex, ex, fmaf(ey, ey, ez * ez)));
  if (x0 >= 1.f) x0 = 0.99999f;
  if (x1 >= 1.f) x1 = 0.99999f;
  if (x2 >= 1.f) x2 = 0.99999f;
  float th0 = theta_from_x(x0), th1 = theta_from_x(x1), th2 = theta_from_x(x2);
  float hh = 0.5f * ((th0 + th1) + th2);
  if (3.14159265358979f - hh < 1e-4f) {
    float cx0 = sqrt_f(fmaxf(fmaf(-x0, x0, 1.f), 0.f));
    float cx1 = sqrt_f(fmaxf(fmaf(-x1, x1, 1.f), 0.f));
    float cx2 = sqrt_f(fmaxf(fmaf(-x2, x2, 1.f), 0.f));
    wjh[f0 * WJS] += (2.f * (x0 * cx0) * d2) * d1;
    wjh[f1 * WJS] += (2.f * (x1 * cx1) * d0) * d2;
    wjh[f2 * WJS] += (2.f * (x2 * cx2) * d1) * d0;
  }
}

// ---------------- Kernel D: MVC weights + deformed ----------------
// 128 threads: wave0 = faces [0,40) of point p=lane, wave1 = faces [40,80).
// Private per-half LDS accumulators (no atomics), stride-65 padding.
__global__ __launch_bounds__(128) void mvc_kernel(
    const float* __restrict__ src,      // (B,3,N)
    const float* __restrict__ cage_t,   // (B,42,3)
    const float* __restrict__ ncage_t,  // (B,42,3)
    const int* __restrict__ faces,      // (80,3)
    float* __restrict__ out_def,        // (B,3,N)
    float* __restrict__ out_w)          // (B,N,42)
{
  __shared__ float4 vpos[NV];
  __shared__ float4 npos[NV];
  __shared__ int fidp[NF];
  __shared__ float wj[2 * NV * WJS];
  __shared__ unsigned long long closeM[2][PPB];
  __shared__ int insideF[2][PPB];

  const float PI_F = 3.14159265358979323846f;
  int tid = threadIdx.x;
  int p   = tid & (PPB - 1);
  int hf  = tid >> 6;
  int b    = blockIdx.x / (NP / PPB);
  int pblk = blockIdx.x % (NP / PPB);
  int gp   = pblk * PPB + p;

  if (tid < NV) {
    const float* cp = cage_t + (size_t)b * NV * 3 + tid * 3;
    vpos[tid] = make_float4(cp[0], cp[1], cp[2], 0.f);
    const float* np_ = ncage_t + (size_t)b * NV * 3 + tid * 3;
    npos[tid] = make_float4(np_[0], np_[1], np_[2], 0.f);
  }
  if (tid < NF) {
    int f0 = faces[3 * tid], f1 = faces[3 * tid + 1], f2 = faces[3 * tid + 2];
    fidp[tid] = f0 | (f1 << 6) | (f2 << 12);
  }
  for (int i = tid; i < 2 * NV * WJS; i += 128) wj[i] = 0.f;
  __syncthreads();

  float qx = src[(size_t)b * 3 * NP + gp];
  float qy = src[(size_t)b * 3 * NP + NP + gp];
  float qz = src[(size_t)b * 3 * NP + 2 * NP + gp];

  int anyInside = 0;
  unsigned long long closeMask = 0ull;
  float* wjh = wj + hf * (NV * WJS) + p;

  #pragma unroll 2
  for (int i = hf * FH; i < hf * FH + FH; i++) {
    int pk = fidp[i];
    int f0 = pk & 63, f1 = (pk >> 6) & 63, f2 = pk >> 12;
    float4 v0 = vpos[f0], v1 = vpos[f1], v2 = vpos[f2];
    float a0x = v0.x - qx, a0y = v0.y - qy, a0z = v0.z - qz;
    float a1x = v1.x - qx, a1y = v1.y - qy, a1z = v1.z - qz;
    float a2x = v2.x - qx, a2y = v2.y - qy, a2z = v2.z - qz;
    float ss0 = fmaf(a0x, a0x, fmaf(a0y, a0y, a0z * a0z));
    float ss1 = fmaf(a1x, a1x, fmaf(a1y, a1y, a1z * a1z));
    float ss2 = fmaf(a2x, a2x, fmaf(a2y, a2y, a2z * a2z));
    if (ss0 < 1e-16f) closeMask |= (1ull << f0);   // d<1e-8 <=> ss<1e-16
    if (ss1 < 1e-16f) closeMask |= (1ull << f1);
    if (ss2 < 1e-16f) closeMask |= (1ull << f2);
    float i0 = rsq_f(ss0), i1 = rsq_f(ss1), i2 = rsq_f(ss2);
    float d0 = ss0 * i0, d1 = ss1 * i1, d2 = ss2 * i2;
    float u0x = a0x * i0, u0y = a0y * i0, u0z = a0z * i0;
    float u1x = a1x * i1, u1y = a1y * i1, u1z = a1z * i1;
    float u2x = a2x * i2, u2y = a2y * i2, u2z = a2z * i2;
    // chord half-lengths via EDGE SUBTRACTION (cancellation-safe; r7 lesson:
    // the dot-product form 1-u.u' loses all relative accuracy for far points)
    float ex = u1x - u2x, ey = u1y - u2y, ez = u1z - u2z;
    float x0 = 0.5f * sqrt_f(fmaf(ex, ex, fmaf(ey, ey, ez * ez)));
    ex = u2x - u0x; ey = u2y - u0y; ez = u2z - u0z;
    float x1 = 0.5f * sqrt_f(fmaf(ex, ex, fmaf(ey, ey, ez * ez)));
    ex = u0x - u1x; ey = u0y - u1y; ez = u0z - u1z;
    float x2 = 0.5f * sqrt_f(fmaf(ex, ex, fmaf(ey, ey, ez * ez)));
    if (x0 >= 1.f) x0 = 0.99999f;     // reference clamp l>=2 -> 1.99998
    if (x1 >= 1.f) x1 = 0.99999f;
    if (x2 >= 1.f) x2 = 0.99999f;
    float cx0 = sqrt_f(fmaxf(fmaf(-x0, x0, 1.f), 0.f));
    float cx1 = sqrt_f(fmaxf(fmaf(-x1, x1, 1.f), 0.f));
    float cx2 = sqrt_f(fmaxf(fmaf(-x2, x2, 1.f), 0.f));
    float th0 = theta_from_x(x0);
    float th1 = theta_from_x(x1);
    float th2 = theta_from_x(x2);
    float hh = 0.5f * ((th0 + th1) + th2);
    if (PI_F - hh < 1e-4f) anyInside = 1;
    float t0 = x0 * cx0, t1 = x1 * cx1, t2 = x2 * cx2;
    float st0 = t0 + t0, st1 = t1 + t1, st2 = t2 + t2;   // sin(theta_i)
    float A1 = x0 * (cx1 * cx2);
    float A2 = x1 * (cx0 * cx2);
    float A3 = x2 * (cx0 * cx1);
    float A4 = x0 * (x1 * x2);
    float sh  = ((A1 + A2) + A3) - A4;     // sin(h)
    float sm0 = ((-A1 + A2) + A3) + A4;    // sin(h-th0)
    float sm1 = ((A1 - A2) + A3) + A4;
    float sm2 = ((A1 + A2) - A3) + A4;
    float twosh = sh + sh;
    float c0 = fmaf(twosh * sm0, rcp_f(st1 * st2), -1.f);
    float c1 = fmaf(twosh * sm1, rcp_f(st2 * st0), -1.f);
    float c2 = fmaf(twosh * sm2, rcp_f(st0 * st1), -1.f);
    c0 = fminf(fmaxf(c0, -0.99999f), 0.99999f);
    c1 = fminf(fmaxf(c1, -0.99999f), 0.99999f);
    c2 = fminf(fmaxf(c2, -0.99999f), 0.99999f);
    float det = u0x * fmaf(u1y, u2z, -(u1z * u2y))
              - u0y * fmaf(u1x, u2z, -(u1z * u2x))
              + u0z * fmaf(u1x, u2y, -(u1y * u2x));
    float sg = (det > 0.f) ? 1.f : ((det < 0.f) ? -1.f : 0.f);
    float sn0 = sg * sqrt_f(fmaf(-c0, c0, 1.f));
    float sn1 = sg * sqrt_f(fmaf(-c1, c1, 1.f));
    float sn2 = sg * sqrt_f(fmaf(-c2, c2, 1.f));
    float w0 = fmaf(-c2, th1, fmaf(-c1, th2, th0)) * rcp_f((d0 * st1) * sn2);
    float w1 = fmaf(-c0, th2, fmaf(-c2, th0, th1)) * rcp_f((d1 * st2) * sn0);
    float w2 = fmaf(-c1, th0, fmaf(-c0, th1, th2)) * rcp_f((d2 * st0) * sn1);
    wjh[f0 * WJS] += w0;      // private region: no atomics
    wjh[f1 * WJS] += w1;
    wjh[f2 * WJS] += w2;
  }

  closeM[hf][p]  = closeMask;
  insideF[hf][p] = anyInside;
  __syncthreads();

  int mIn = insideF[0][p] | insideF[1][p];
  unsigned long long mCl = closeM[0][p] | closeM[1][p];

  if (mIn) {   // cold: exact `where(inside, ...)` semantics
    for (int c = 0; c < NV; c++) wjh[c * WJS] = 0.f;
    #pragma unroll 1
    for (int i = hf * FH; i < hf * FH + FH; i++) {
      int pk = fidp[i];
      inside_face_rt(pk & 63, (pk >> 6) & 63, pk >> 12, vpos, qx, qy, qz, wjh);
    }
  }
  __syncthreads();

  if (tid < PPB) {
    float sum = 0.f;
    for (int c = 0; c < NV; c++) {
      float w = wj[c * WJS + p] + wj[(NV + c) * WJS + p];
      if (mCl) w = ((mCl >> c) & 1ull) ? 1.f : 0.f;
      wj[c * WJS + p] = w;
      sum += w;
    }
    if (sum == 0.f) sum = 1.f;
    float inv = rcp_f(sum);
    float ax = 0.f, ay = 0.f, az = 0.f;
    for (int c = 0; c < NV; c++) {
      float w = wj[c * WJS + p] * inv;
      wj[c * WJS + p] = w;
      float4 n = npos[c];
      ax = fmaf(w, n.x, ax);
      ay = fmaf(w, n.y, ay);
      az = fmaf(w, n.z, az);
    }
    out_def[(size_t)b * 3 * NP + gp]          = ax;
    out_def[(size_t)b * 3 * NP + NP + gp]     = ay;
    out_def[(size_t)b * 3 * NP + 2 * NP + gp] = az;
  }
  __syncthreads();

  // coalesced weight write; stride 65 -> conflict-free transposed read
  float* wbase = out_w + ((size_t)b * NP + pblk * PPB) * NV;
  for (int idx = tid; idx < PPB * NV; idx += 128) {
    int pp = idx / NV;
    int c  = idx - pp * NV;
    wbase[idx] = wj[c * WJS + pp];
  }
}

// ---------------- shared split-K linear body (round-3 proven) ----------------
__device__ __forceinline__ void splitk_body(
    const float* in0, const float* in1,
    const float* W, const float* bias, float* out,
    int FI, int FO, int relu, int ox, int bb, int tid,
    float* sIn, float (*part)[64])
{
  for (int i = tid; i < FI; i += 256) {
    float v;
    if (in1) v = (i < FEAT) ? in0[(size_t)bb * FEAT + i]
                            : in1[(size_t)bb * FEAT + i - FEAT];
    else     v = in0[(size_t)bb * FI + i];
    sIn[i] = v;
  }
  __syncthreads();
  int o = ox * 64 + (tid & 63);
  int kk = tid >> 6;
  int seg = FI >> 2;
  float acc = 0.f;
  const float* wp = W + o;
  #pragma unroll 4
  for (int i = kk * seg; i < (kk + 1) * seg; i++)
    acc = fmaf(sIn[i], wp[(size_t)i * FO], acc);
  part[kk][tid & 63] = acc;
  __syncthreads();
  if (tid < 64) {
    float r = ((part[0][tid] + part[1][tid]) + (part[2][tid] + part[3][tid]))
              + bias[o];
    out[(size_t)bb * FO + o] = relu ? fmaxf(r, 0.f) : r;
  }
}

// ---------------- Kernel A: cage_opt (blocks<672) + L1 split-K (672..799) ----
__global__ __launch_bounds__(256) void cage_l1_kernel(
    const float* __restrict__ tmpl, const float* __restrict__ src,
    const float* __restrict__ sf, const float* __restrict__ tf,
    const float* __restrict__ W1, const float* __restrict__ b1,
    float* __restrict__ cage, float* __restrict__ h1)
{
  __shared__ float red[8];
  __shared__ float sIn[512];
  __shared__ float part[4][64];
  int tid = threadIdx.x;

  if (blockIdx.x < BB * NV) {
    int b = blockIdx.x / NV;
    int v = blockIdx.x % NV;
    const float* sp = src + (size_t)b * 3 * NP;
    float cx = tmpl[v], cy = tmpl[NV + v], cz = tmpl[2 * NV + v];
    int k = 0;
    while (true) {
      float m = 3.4e38f;
      for (int i = tid; i < NP; i += 256) {
        float dx = __fsub_rn(cx, sp[i]);
        float dy = __fsub_rn(cy, sp[NP + i]);
        float dz = __fsub_rn(cz, sp[2 * NP + i]);
        float ss = __fadd_rn(__fadd_rn(__fmul_rn(dx, dx), __fmul_rn(dy, dy)),
                             __fmul_rn(dz, dz));
        m = fminf(m, ss);
      }
      #pragma unroll
      for (int off = 32; off > 0; off >>= 1)
        m = fminf(m, __shfl_down(m, off, 64));
      int wid = tid >> 6;
      __syncthreads();
      if ((tid & 63) == 0) red[wid] = m;
      __syncthreads();
      if (tid == 0) {
        float mm = fminf(fminf(red[0], red[1]), fminf(red[2], red[3]));
        red[4] = sqrtf(mm);
      }
      __syncthreads();
      float mind = red[4];
      if (mind > 0.4f && k < 100) {
        cx = __fsub_rn(cx, __fmul_rn(0.01f, cx));
        cy = __fsub_rn(cy, __fmul_rn(0.01f, cy));
        cz = __fsub_rn(cz, __fmul_rn(0.01f, cz));
        k++;
      } else {
        break;
      }
    }
    if (tid == 0) {
      cage[(size_t)b * 3 * NV + v]          = cx;
      cage[(size_t)b * 3 * NV + NV + v]     = cy;
      cage[(size_t)b * 3 * NV + 2 * NV + v] = cz;
    }
  } else {
    int idx = blockIdx.x - BB * NV;   // 0..127
    splitk_body(sf, tf, W1, b1, h1, 512, 512, 1, idx & 7, idx >> 3,
                tid, sIn, part);
  }
}

// ---------------- standalone split-K linear (round-3 proven) ----------------
__global__ __launch_bounds__(256) void linear_splitk(
    const float* __restrict__ in0, const float* __restrict__ in1,
    const float* __restrict__ W, const float* __restrict__ bias,
    float* __restrict__ out, int FI, int FO, int relu)
{
  __shared__ float sIn[512];
  __shared__ float part[4][64];
  splitk_body(in0, in1, W, bias, out, FI, FO, relu,
              blockIdx.x, blockIdx.y, threadIdx.x, sIn, part);
}

// ---------------- L4 + cage finalize (round-3 proven) ----------------
__global__ __launch_bounds__(128) void l4_finalize_kernel(
    const float* __restrict__ h3,
    const float* __restrict__ W4, const float* __restrict__ b4,
    const float* __restrict__ cage,
    float* __restrict__ out_io,
    float* __restrict__ cage_t,
    float* __restrict__ ncage_t)
{
  __shared__ float sIn[256];
  int bb = blockIdx.x;
  int tid = threadIdx.x;
  sIn[tid] = h3[(size_t)bb * 256 + tid];
  sIn[tid + 128] = h3[(size_t)bb * 256 + tid + 128];
  __syncthreads();
  if (tid < 126) {
    float acc = b4[tid];
    const float* wp = W4 + tid;
    #pragma unroll 4
    for (int i = 0; i < 256; i++) acc = fmaf(sIn[i], wp[(size_t)i * 126], acc);
    out_io[(size_t)bb * 126 + tid] = acc;
    float c  = cage[(size_t)bb * 126 + tid];
    float nc = c + acc;
    int d = tid / NV, v = tid - d * NV;
    cage_t[(size_t)bb * NV * 3 + v * 3 + d]  = c;
    ncage_t[(size_t)bb * NV * 3 + v * 3 + d] = nc;
  }
}

extern "C" void kernel_launch(void* const* d_in, const int* in_sizes, int n_in,
                              void* d_out, int out_size, void* d_ws, size_t ws_size,
                              hipStream_t stream) {
  (void)in_sizes; (void)n_in; (void)out_size; (void)d_ws; (void)ws_size;
  const float* src   = (const float*)d_in[0];
  const float* sf    = (const float*)d_in[2];
  const float* tf    = (const float*)d_in[3];
  const float* tmpl  = (const float*)d_in[4];
  const int*   faces = (const int*)d_in[5];
  const float* W1 = (const float*)d_in[6];  const float* b1 = (const float*)d_in[7];
  const float* W2 = (const float*)d_in[8];  const float* b2 = (const float*)d_in[9];
  const float* W3 = (const float*)d_in[10]; const float* b3 = (const float*)d_in[11];
  const float* W4 = (const float*)d_in[12]; const float* b4 = (const float*)d_in[13];

  float* out = (float*)d_out;
  float* out_cage_t  = out;                 // (16,42,3)   2016
  float* out_ncage_t = out + 2016;          // (16,42,3)   2016
  float* out_def     = out + 4032;          // (16,3,8192) 393216
  float* out_w       = out + 397248;        // (16,8192,42) 5505024
  float* out_io      = out + 5902272;       // (16,126)    2016

  // scratch carved out of the weights region (fully overwritten by mvc_kernel)
  float* s_cage = out_w;           // 2016
  float* s_h1   = out_w + 2016;    // 8192
  float* s_h2   = out_w + 10208;   // 8192
  float* s_h3   = out_w + 18400;   // 4096

  cage_l1_kernel<<<dim3(BB * NV + 128), dim3(256), 0, stream>>>(
      tmpl, src, sf, tf, W1, b1, s_cage, s_h1);
  linear_splitk<<<dim3(8, BB), dim3(256), 0, stream>>>(s_h1, nullptr, W2, b2, s_h2, 512, 512, 1);
  linear_splitk<<<dim3(4, BB), dim3(256), 0, stream>>>(s_h2, nullptr, W3, b3, s_h3, 512, 256, 1);
  l4_finalize_kernel<<<dim3(BB), dim3(128), 0, stream>>>(
      s_h3, W4, b4, s_cage, out_io, out_cage_t, out_ncage_t);
  mvc_kernel<<<dim3(BB * (NP / PPB)), dim3(128), 0, stream>>>(
      src, out_cage_t, out_ncage_t, faces, out_def, out_w);
}

// Round 9
// 162.005 us; speedup vs baseline: 1.6989x; 1.0189x over previous
//
#include <hip/hip_runtime.h>
#include <math.h>

#define BB 16
#define NP 8192
#define NV 42
#define NF 80
#define FEAT 256
#define PPB 64           // points per block (mvc)
#define FH  40           // faces per half-wave
#define WJS 65           // padded LDS stride (65%32==1 -> transposed epilogue conflict-free)

__device__ __forceinline__ float rcp_f(float x)  { return __builtin_amdgcn_rcpf(x); }
__device__ __forceinline__ float rsq_f(float x)  { return __builtin_amdgcn_rsqf(x); }
__device__ __forceinline__ float sqrt_f(float x) { return __builtin_amdgcn_sqrtf(x); }

// theta = 2*asin(x), x in [0,1). Branchless, |err|~1e-5. (validated r2-r8)
__device__ __forceinline__ float theta_from_x(float x) {
  bool big = x > 0.5f;
  float z = big ? fmaf(-0.5f, x, 0.5f) : x * x;
  float s = big ? sqrt_f(z) : x;
  float P = fmaf(z, 0.022371875f, 0.030381944f);
  P = fmaf(z, P, 0.044642857f);
  P = fmaf(z, P, 0.075f);
  P = fmaf(z, P, 0.16666667f);
  float r = fmaf(s * z, P, s);
  return big ? fmaf(-4.f, r, 3.14159265358979f) : 2.f * r;
}

// cold path: runtime face recompute, inside-formula accumulate into private region
__device__ __attribute__((noinline)) void inside_face_rt(
    int f0, int f1, int f2, const float4* vpos,
    float qx, float qy, float qz, float* wjh)   // wjh = &wj[hf*NV*WJS + p]
{
  float4 v0 = vpos[f0], v1 = vpos[f1], v2 = vpos[f2];
  float a0x = v0.x - qx, a0y = v0.y - qy, a0z = v0.z - qz;
  float a1x = v1.x - qx, a1y = v1.y - qy, a1z = v1.z - qz;
  float a2x = v2.x - qx, a2y = v2.y - qy, a2z = v2.z - qz;
  float ss0 = fmaf(a0x, a0x, fmaf(a0y, a0y, a0z * a0z));
  float ss1 = fmaf(a1x, a1x, fmaf(a1y, a1y, a1z * a1z));
  float ss2 = fmaf(a2x, a2x, fmaf(a2y, a2y, a2z * a2z));
  float i0 = rsq_f(ss0), i1 = rsq_f(ss1), i2 = rsq_f(ss2);
  float d0 = ss0 * i0, d1 = ss1 * i1, d2 = ss2 * i2;
  float u0x = a0x * i0, u0y = a0y * i0, u0z = a0z * i0;
  float u1x = a1x * i1, u1y = a1y * i1, u1z = a1z * i1;
  float u2x = a2x * i2, u2y = a2y * i2, u2z = a2z * i2;
  float ex = u1x - u2x, ey = u1y - u2y, ez = u1z - u2z;
  float x0 = 0.5f * sqrt_f(fmaf(ex, ex, fmaf(ey, ey, ez * ez)));
  ex = u2x - u0x; ey = u2y - u0y; ez = u2z - u0z;
  float x1 = 0.5f * sqrt_f(fmaf(ex, ex, fmaf(ey, ey, ez * ez)));
  ex = u0x - u1x; ey = u0y - u1y; ez = u0z - u1z;
  float x2 = 0.5f * sqrt_f(fmaf(ex, ex, fmaf(ey, ey, ez * ez)));
  if (x0 >= 1.f) x0 = 0.99999f;
  if (x1 >= 1.f) x1 = 0.99999f;
  if (x2 >= 1.f) x2 = 0.99999f;
  float th0 = theta_from_x(x0), th1 = theta_from_x(x1), th2 = theta_from_x(x2);
  float hh = 0.5f * ((th0 + th1) + th2);
  if (3.14159265358979f - hh < 1e-4f) {
    float cx0 = sqrt_f(fmaxf(fmaf(-x0, x0, 1.f), 0.f));
    float cx1 = sqrt_f(fmaxf(fmaf(-x1, x1, 1.f), 0.f));
    float cx2 = sqrt_f(fmaxf(fmaf(-x2, x2, 1.f), 0.f));
    wjh[f0 * WJS] += (2.f * (x0 * cx0) * d2) * d1;
    wjh[f1 * WJS] += (2.f * (x1 * cx1) * d0) * d2;
    wjh[f2 * WJS] += (2.f * (x2 * cx2) * d1) * d0;
  }
}

// ---------------- Kernel D: MVC weights + deformed ----------------
// 128 threads: wave0 = faces [0,40) of point p=lane, wave1 = faces [40,80).
// Two faces (j, j+20) evaluated per iteration as INDEPENDENT chains for ILP.
__global__ __launch_bounds__(128) void mvc_kernel(
    const float* __restrict__ src,      // (B,3,N)
    const float* __restrict__ cage_t,   // (B,42,3)
    const float* __restrict__ ncage_t,  // (B,42,3)
    const int* __restrict__ faces,      // (80,3)
    float* __restrict__ out_def,        // (B,3,N)
    float* __restrict__ out_w)          // (B,N,42)
{
  __shared__ float4 vpos[NV];
  __shared__ float4 npos[NV];
  __shared__ int fidp[NF];
  __shared__ float wj[2 * NV * WJS];
  __shared__ unsigned long long closeM[2][PPB];
  __shared__ int insideF[2][PPB];

  const float PI_F = 3.14159265358979323846f;
  int tid = threadIdx.x;
  int p   = tid & (PPB - 1);
  int hf  = tid >> 6;
  int b    = blockIdx.x / (NP / PPB);
  int pblk = blockIdx.x % (NP / PPB);
  int gp   = pblk * PPB + p;

  if (tid < NV) {
    const float* cp = cage_t + (size_t)b * NV * 3 + tid * 3;
    vpos[tid] = make_float4(cp[0], cp[1], cp[2], 0.f);
    const float* np_ = ncage_t + (size_t)b * NV * 3 + tid * 3;
    npos[tid] = make_float4(np_[0], np_[1], np_[2], 0.f);
  }
  if (tid < NF) {
    int f0 = faces[3 * tid], f1 = faces[3 * tid + 1], f2 = faces[3 * tid + 2];
    fidp[tid] = f0 | (f1 << 6) | (f2 << 12);
  }
  for (int i = tid; i < 2 * NV * WJS; i += 128) wj[i] = 0.f;
  __syncthreads();

  float qx = src[(size_t)b * 3 * NP + gp];
  float qy = src[(size_t)b * 3 * NP + NP + gp];
  float qz = src[(size_t)b * 3 * NP + 2 * NP + gp];

  int anyInside = 0;
  unsigned long long closeMask = 0ull;
  float* wjh = wj + hf * (NV * WJS) + p;

  // one face, full r8-validated math; independent locals per instantiation
  auto face_eval = [&](int i, int& f0, int& f1, int& f2,
                       float& w0, float& w1, float& w2) {
    int pk = fidp[i];
    f0 = pk & 63; f1 = (pk >> 6) & 63; f2 = pk >> 12;
    float4 v0 = vpos[f0], v1 = vpos[f1], v2 = vpos[f2];
    float a0x = v0.x - qx, a0y = v0.y - qy, a0z = v0.z - qz;
    float a1x = v1.x - qx, a1y = v1.y - qy, a1z = v1.z - qz;
    float a2x = v2.x - qx, a2y = v2.y - qy, a2z = v2.z - qz;
    float ss0 = fmaf(a0x, a0x, fmaf(a0y, a0y, a0z * a0z));
    float ss1 = fmaf(a1x, a1x, fmaf(a1y, a1y, a1z * a1z));
    float ss2 = fmaf(a2x, a2x, fmaf(a2y, a2y, a2z * a2z));
    if (ss0 < 1e-16f) closeMask |= (1ull << f0);   // d<1e-8 <=> ss<1e-16
    if (ss1 < 1e-16f) closeMask |= (1ull << f1);
    if (ss2 < 1e-16f) closeMask |= (1ull << f2);
    float i0 = rsq_f(ss0), i1 = rsq_f(ss1), i2 = rsq_f(ss2);
    float d0 = ss0 * i0, d1 = ss1 * i1, d2 = ss2 * i2;
    float u0x = a0x * i0, u0y = a0y * i0, u0z = a0z * i0;
    float u1x = a1x * i1, u1y = a1y * i1, u1z = a1z * i1;
    float u2x = a2x * i2, u2y = a2y * i2, u2z = a2z * i2;
    // chord half-lengths via EDGE SUBTRACTION (r7 lesson: never 1-u.u')
    float ex = u1x - u2x, ey = u1y - u2y, ez = u1z - u2z;
    float x0 = 0.5f * sqrt_f(fmaf(ex, ex, fmaf(ey, ey, ez * ez)));
    ex = u2x - u0x; ey = u2y - u0y; ez = u2z - u0z;
    float x1 = 0.5f * sqrt_f(fmaf(ex, ex, fmaf(ey, ey, ez * ez)));
    ex = u0x - u1x; ey = u0y - u1y; ez = u0z - u1z;
    float x2 = 0.5f * sqrt_f(fmaf(ex, ex, fmaf(ey, ey, ez * ez)));
    if (x0 >= 1.f) x0 = 0.99999f;     // reference clamp l>=2 -> 1.99998
    if (x1 >= 1.f) x1 = 0.99999f;
    if (x2 >= 1.f) x2 = 0.99999f;
    float cx0 = sqrt_f(fmaxf(fmaf(-x0, x0, 1.f), 0.f));
    float cx1 = sqrt_f(fmaxf(fmaf(-x1, x1, 1.f), 0.f));
    float cx2 = sqrt_f(fmaxf(fmaf(-x2, x2, 1.f), 0.f));
    float th0 = theta_from_x(x0);
    float th1 = theta_from_x(x1);
    float th2 = theta_from_x(x2);
    float hh = 0.5f * ((th0 + th1) + th2);
    if (PI_F - hh < 1e-4f) anyInside = 1;
    float t0 = x0 * cx0, t1 = x1 * cx1, t2 = x2 * cx2;
    float st0 = t0 + t0, st1 = t1 + t1, st2 = t2 + t2;   // sin(theta_i)
    float A1 = x0 * (cx1 * cx2);
    float A2 = x1 * (cx0 * cx2);
    float A3 = x2 * (cx0 * cx1);
    float A4 = x0 * (x1 * x2);
    float sh  = ((A1 + A2) + A3) - A4;     // sin(h)
    float sm0 = ((-A1 + A2) + A3) + A4;    // sin(h-th0)
    float sm1 = ((A1 - A2) + A3) + A4;
    float sm2 = ((A1 + A2) - A3) + A4;
    float twosh = sh + sh;
    float c0 = fmaf(twosh * sm0, rcp_f(st1 * st2), -1.f);
    float c1 = fmaf(twosh * sm1, rcp_f(st2 * st0), -1.f);
    float c2 = fmaf(twosh * sm2, rcp_f(st0 * st1), -1.f);
    c0 = fminf(fmaxf(c0, -0.99999f), 0.99999f);
    c1 = fminf(fmaxf(c1, -0.99999f), 0.99999f);
    c2 = fminf(fmaxf(c2, -0.99999f), 0.99999f);
    float det = u0x * fmaf(u1y, u2z, -(u1z * u2y))
              - u0y * fmaf(u1x, u2z, -(u1z * u2x))
              + u0z * fmaf(u1x, u2y, -(u1y * u2x));
    float sg = (det > 0.f) ? 1.f : ((det < 0.f) ? -1.f : 0.f);
    float sn0 = sg * sqrt_f(fmaf(-c0, c0, 1.f));
    float sn1 = sg * sqrt_f(fmaf(-c1, c1, 1.f));
    float sn2 = sg * sqrt_f(fmaf(-c2, c2, 1.f));
    w0 = fmaf(-c2, th1, fmaf(-c1, th2, th0)) * rcp_f((d0 * st1) * sn2);
    w1 = fmaf(-c0, th2, fmaf(-c2, th0, th1)) * rcp_f((d1 * st2) * sn0);
    w2 = fmaf(-c1, th0, fmaf(-c0, th1, th2)) * rcp_f((d2 * st0) * sn1);
  };

  #pragma unroll 1
  for (int j = 0; j < FH / 2; j++) {      // two independent chains per iter
    int fa0, fa1, fa2, fb0, fb1, fb2;
    float wa0, wa1, wa2, wb0, wb1, wb2;
    face_eval(hf * FH + j,            fa0, fa1, fa2, wa0, wa1, wa2);
    face_eval(hf * FH + FH / 2 + j,   fb0, fb1, fb2, wb0, wb1, wb2);
    wjh[fa0 * WJS] += wa0;
    wjh[fa1 * WJS] += wa1;
    wjh[fa2 * WJS] += wa2;
    wjh[fb0 * WJS] += wb0;
    wjh[fb1 * WJS] += wb1;
    wjh[fb2 * WJS] += wb2;
  }

  closeM[hf][p]  = closeMask;
  insideF[hf][p] = anyInside;
  __syncthreads();

  int mIn = insideF[0][p] | insideF[1][p];
  unsigned long long mCl = closeM[0][p] | closeM[1][p];

  if (mIn) {   // cold: exact `where(inside, ...)` semantics
    for (int c = 0; c < NV; c++) wjh[c * WJS] = 0.f;
    #pragma unroll 1
    for (int i = hf * FH; i < hf * FH + FH; i++) {
      int pk = fidp[i];
      inside_face_rt(pk & 63, (pk >> 6) & 63, pk >> 12, vpos, qx, qy, qz, wjh);
    }
  }
  __syncthreads();

  if (tid < PPB) {
    float sum = 0.f;
    for (int c = 0; c < NV; c++) {
      float w = wj[c * WJS + p] + wj[(NV + c) * WJS + p];
      if (mCl) w = ((mCl >> c) & 1ull) ? 1.f : 0.f;
      wj[c * WJS + p] = w;
      sum += w;
    }
    if (sum == 0.f) sum = 1.f;
    float inv = rcp_f(sum);
    float ax = 0.f, ay = 0.f, az = 0.f;
    for (int c = 0; c < NV; c++) {
      float w = wj[c * WJS + p] * inv;
      wj[c * WJS + p] = w;
      float4 n = npos[c];
      ax = fmaf(w, n.x, ax);
      ay = fmaf(w, n.y, ay);
      az = fmaf(w, n.z, az);
    }
    out_def[(size_t)b * 3 * NP + gp]          = ax;
    out_def[(size_t)b * 3 * NP + NP + gp]     = ay;
    out_def[(size_t)b * 3 * NP + 2 * NP + gp] = az;
  }
  __syncthreads();

  // coalesced weight write; stride 65 -> conflict-free transposed read
  float* wbase = out_w + ((size_t)b * NP + pblk * PPB) * NV;
  for (int idx = tid; idx < PPB * NV; idx += 128) {
    int pp = idx / NV;
    int c  = idx - pp * NV;
    wbase[idx] = wj[c * WJS + pp];
  }
}

// ---------------- shared split-K linear body (round-3 proven) ----------------
__device__ __forceinline__ void splitk_body(
    const float* in0, const float* in1,
    const float* W, const float* bias, float* out,
    int FI, int FO, int relu, int ox, int bb, int tid,
    float* sIn, float (*part)[64])
{
  for (int i = tid; i < FI; i += 256) {
    float v;
    if (in1) v = (i < FEAT) ? in0[(size_t)bb * FEAT + i]
                            : in1[(size_t)bb * FEAT + i - FEAT];
    else     v = in0[(size_t)bb * FI + i];
    sIn[i] = v;
  }
  __syncthreads();
  int o = ox * 64 + (tid & 63);
  int kk = tid >> 6;
  int seg = FI >> 2;
  float acc = 0.f;
  const float* wp = W + o;
  #pragma unroll 4
  for (int i = kk * seg; i < (kk + 1) * seg; i++)
    acc = fmaf(sIn[i], wp[(size_t)i * FO], acc);
  part[kk][tid & 63] = acc;
  __syncthreads();
  if (tid < 64) {
    float r = ((part[0][tid] + part[1][tid]) + (part[2][tid] + part[3][tid]))
              + bias[o];
    out[(size_t)bb * FO + o] = relu ? fmaxf(r, 0.f) : r;
  }
}

// ---------------- Kernel A: cage_opt (blocks<672) + L1 split-K (672..799) ----
__global__ __launch_bounds__(256) void cage_l1_kernel(
    const float* __restrict__ tmpl, const float* __restrict__ src,
    const float* __restrict__ sf, const float* __restrict__ tf,
    const float* __restrict__ W1, const float* __restrict__ b1,
    float* __restrict__ cage, float* __restrict__ h1)
{
  __shared__ float red[8];
  __shared__ float sIn[512];
  __shared__ float part[4][64];
  int tid = threadIdx.x;

  if (blockIdx.x < BB * NV) {
    int b = blockIdx.x / NV;
    int v = blockIdx.x % NV;
    const float* sp = src + (size_t)b * 3 * NP;
    float cx = tmpl[v], cy = tmpl[NV + v], cz = tmpl[2 * NV + v];
    int k = 0;
    while (true) {
      float m = 3.4e38f;
      for (int i = tid; i < NP; i += 256) {
        float dx = __fsub_rn(cx, sp[i]);
        float dy = __fsub_rn(cy, sp[NP + i]);
        float dz = __fsub_rn(cz, sp[2 * NP + i]);
        float ss = __fadd_rn(__fadd_rn(__fmul_rn(dx, dx), __fmul_rn(dy, dy)),
                             __fmul_rn(dz, dz));
        m = fminf(m, ss);
      }
      #pragma unroll
      for (int off = 32; off > 0; off >>= 1)
        m = fminf(m, __shfl_down(m, off, 64));
      int wid = tid >> 6;
      __syncthreads();
      if ((tid & 63) == 0) red[wid] = m;
      __syncthreads();
      if (tid == 0) {
        float mm = fminf(fminf(red[0], red[1]), fminf(red[2], red[3]));
        red[4] = sqrtf(mm);
      }
      __syncthreads();
      float mind = red[4];
      if (mind > 0.4f && k < 100) {
        cx = __fsub_rn(cx, __fmul_rn(0.01f, cx));
        cy = __fsub_rn(cy, __fmul_rn(0.01f, cy));
        cz = __fsub_rn(cz, __fmul_rn(0.01f, cz));
        k++;
      } else {
        break;
      }
    }
    if (tid == 0) {
      cage[(size_t)b * 3 * NV + v]          = cx;
      cage[(size_t)b * 3 * NV + NV + v]     = cy;
      cage[(size_t)b * 3 * NV + 2 * NV + v] = cz;
    }
  } else {
    int idx = blockIdx.x - BB * NV;   // 0..127
    splitk_body(sf, tf, W1, b1, h1, 512, 512, 1, idx & 7, idx >> 3,
                tid, sIn, part);
  }
}

// ---------------- standalone split-K linear (round-3 proven) ----------------
__global__ __launch_bounds__(256) void linear_splitk(
    const float* __restrict__ in0, const float* __restrict__ in1,
    const float* __restrict__ W, const float* __restrict__ bias,
    float* __restrict__ out, int FI, int FO, int relu)
{
  __shared__ float sIn[512];
  __shared__ float part[4][64];
  splitk_body(in0, in1, W, bias, out, FI, FO, relu,
              blockIdx.x, blockIdx.y, threadIdx.x, sIn, part);
}

// ---------------- L4 + cage finalize (round-3 proven) ----------------
__global__ __launch_bounds__(128) void l4_finalize_kernel(
    const float* __restrict__ h3,
    const float* __restrict__ W4, const float* __restrict__ b4,
    const float* __restrict__ cage,
    float* __restrict__ out_io,
    float* __restrict__ cage_t,
    float* __restrict__ ncage_t)
{
  __shared__ float sIn[256];
  int bb = blockIdx.x;
  int tid = threadIdx.x;
  sIn[tid] = h3[(size_t)bb * 256 + tid];
  sIn[tid + 128] = h3[(size_t)bb * 256 + tid + 128];
  __syncthreads();
  if (tid < 126) {
    float acc = b4[tid];
    const float* wp = W4 + tid;
    #pragma unroll 4
    for (int i = 0; i < 256; i++) acc = fmaf(sIn[i], wp[(size_t)i * 126], acc);
    out_io[(size_t)bb * 126 + tid] = acc;
    float c  = cage[(size_t)bb * 126 + tid];
    float nc = c + acc;
    int d = tid / NV, v = tid - d * NV;
    cage_t[(size_t)bb * NV * 3 + v * 3 + d]  = c;
    ncage_t[(size_t)bb * NV * 3 + v * 3 + d] = nc;
  }
}

extern "C" void kernel_launch(void* const* d_in, const int* in_sizes, int n_in,
                              void* d_out, int out_size, void* d_ws, size_t ws_size,
                              hipStream_t stream) {
  (void)in_sizes; (void)n_in; (void)out_size; (void)d_ws; (void)ws_size;
  const float* src   = (const float*)d_in[0];
  const float* sf    = (const float*)d_in[2];
  const float* tf    = (const float*)d_in[3];
  const float* tmpl  = (const float*)d_in[4];
  const int*   faces = (const int*)d_in[5];
  const float* W1 = (const float*)d_in[6];  const float* b1 = (const float*)d_in[7];
  const float* W2 = (const float*)d_in[8];  const float* b2 = (const float*)d_in[9];
  const float* W3 = (const float*)d_in[10]; const float* b3 = (const float*)d_in[11];
  const float* W4 = (const float*)d_in[12]; const float* b4 = (const float*)d_in[13];

  float* out = (float*)d_out;
  float* out_cage_t  = out;                 // (16,42,3)   2016
  float* out_ncage_t = out + 2016;          // (16,42,3)   2016
  float* out_def     = out + 4032;          // (16,3,8192) 393216
  float* out_w       = out + 397248;        // (16,8192,42) 5505024
  float* out_io      = out + 5902272;       // (16,126)    2016

  // scratch carved out of the weights region (fully overwritten by mvc_kernel)
  float* s_cage = out_w;           // 2016
  float* s_h1   = out_w + 2016;    // 8192
  float* s_h2   = out_w + 10208;   // 8192
  float* s_h3   = out_w + 18400;   // 4096

  cage_l1_kernel<<<dim3(BB * NV + 128), dim3(256), 0, stream>>>(
      tmpl, src, sf, tf, W1, b1, s_cage, s_h1);
  linear_splitk<<<dim3(8, BB), dim3(256), 0, stream>>>(s_h1, nullptr, W2, b2, s_h2, 512, 512, 1);
  linear_splitk<<<dim3(4, BB), dim3(256), 0, stream>>>(s_h2, nullptr, W3, b3, s_h3, 512, 256, 1);
  l4_finalize_kernel<<<dim3(BB), dim3(128), 0, stream>>>(
      s_h3, W4, b4, s_cage, out_io, out_cage_t, out_ncage_t);
  mvc_kernel<<<dim3(BB * (NP / PPB)), dim3(128), 0, stream>>>(
      src, out_cage_t, out_ncage_t, faces, out_def, out_w);
}